// Round 2
// baseline (576.126 us; speedup 1.0000x reference)
//
#include <hip/hip_runtime.h>
#include <hip/hip_bf16.h>

#define LRELU_ALPHA 0.2f
#define NEG_BIG (-9e15f)

typedef __attribute__((ext_vector_type(8))) __bf16 bf16x8;
typedef __attribute__((ext_vector_type(4))) float f32x4;
typedef __attribute__((ext_vector_type(8))) unsigned short u16x8;

__device__ __forceinline__ unsigned short f2bf(float f) {
  unsigned int u = __float_as_uint(f);
  u += 0x7fffu + ((u >> 16) & 1u);   // round-to-nearest-even
  return (unsigned short)(u >> 16);
}

// ---------------- adj bit-pack: bits[i][w] = 32 adjacency bits ----------------
__global__ __launch_bounds__(256) void pack_adj_k(
    const int* __restrict__ adj, unsigned* __restrict__ bits)
{
  size_t i = blockIdx.x;
  const int* arow = adj + i * 8192;
  unsigned* brow = bits + i * 256;
  int t = threadIdx.x;
  int l = t & 63;
#pragma unroll
  for (int it = 0; it < 32; ++it) {
    int j = it * 256 + t;
    unsigned long long m = __ballot(arow[j] > 0);
    if (l == 0) brow[j >> 5] = (unsigned)m;
    else if (l == 32) brow[j >> 5] = (unsigned)(m >> 32);
  }
}

// ---------------- fp32 tiled GEMM: C[M][Nc] = A[M][K] @ B[K][Nc] ----------------
__global__ __launch_bounds__(256) void gemm_f32_k(
    const float* __restrict__ A, const float* __restrict__ B,
    float* __restrict__ C, int M, int K, int Ncols)
{
  __shared__ float As[128][17];
  __shared__ float Bs[16][65];
  int t = threadIdx.x;
  int row0 = blockIdx.x * 128;
  int col0 = blockIdx.y * 64;
  int ty = t >> 4, tx = t & 15;
  float acc[8][4];
#pragma unroll
  for (int i = 0; i < 8; ++i)
#pragma unroll
    for (int j = 0; j < 4; ++j) acc[i][j] = 0.f;

  for (int kt = 0; kt < K; kt += 16) {
    __syncthreads();
    {
      int r = t >> 1, h = t & 1;
      const float4* src = (const float4*)(A + (size_t)(row0 + r) * K + kt + h * 8);
      float4 v0 = src[0], v1 = src[1];
      float* dst = &As[r][h * 8];
      dst[0]=v0.x; dst[1]=v0.y; dst[2]=v0.z; dst[3]=v0.w;
      dst[4]=v1.x; dst[5]=v1.y; dst[6]=v1.z; dst[7]=v1.w;
    }
    {
      int kr = t >> 4, seg = t & 15;
      const float4* src = (const float4*)(B + (size_t)(kt + kr) * Ncols + col0 + seg * 4);
      float4 v = src[0];
      float* dst = &Bs[kr][seg * 4];
      dst[0]=v.x; dst[1]=v.y; dst[2]=v.z; dst[3]=v.w;
    }
    __syncthreads();
#pragma unroll
    for (int k = 0; k < 16; ++k) {
      float bb[4];
#pragma unroll
      for (int j = 0; j < 4; ++j) bb[j] = Bs[k][tx * 4 + j];
#pragma unroll
      for (int i = 0; i < 8; ++i) {
        float aa = As[ty * 8 + i][k];
#pragma unroll
        for (int j = 0; j < 4; ++j) acc[i][j] = fmaf(aa, bb[j], acc[i][j]);
      }
    }
  }
#pragma unroll
  for (int i = 0; i < 8; ++i) {
    float4 v = make_float4(acc[i][0], acc[i][1], acc[i][2], acc[i][3]);
    *(float4*)(C + (size_t)(row0 + ty * 8 + i) * Ncols + col0 + tx * 4) = v;
  }
}

// ---------------- e1/e2 vectors: wave per row ----------------
__global__ __launch_bounds__(256) void calc_e_k(
    const float* __restrict__ Wh, const float* __restrict__ a,
    float* __restrict__ e1, float* __restrict__ e2, int F)
{
  int row = blockIdx.x * 4 + (threadIdx.x >> 6);
  int l = threadIdx.x & 63;
  const float* r = Wh + (size_t)row * F;
  float s1 = 0.f, s2 = 0.f;
  for (int f = l; f < F; f += 64) {
    float v = r[f];
    s1 += v * a[f];
    s2 += v * a[F + f];
  }
#pragma unroll
  for (int off = 32; off; off >>= 1) {
    s1 += __shfl_down(s1, off);
    s2 += __shfl_down(s2, off);
  }
  if (l == 0) { e1[row] = s1; e2[row] = s2; }
}

// ---------------- transpose + fp32->bf16: out[c][r] = bf16(in[r][c]) ----------------
__global__ void transpose_bf16_k(const float* __restrict__ in, unsigned short* __restrict__ out,
                                 int R, int Cc)
{
  __shared__ float tile[32][33];
  int tx = threadIdx.x, ty = threadIdx.y;
  int c0 = blockIdx.x * 32, r0 = blockIdx.y * 32;
  int c = c0 + tx;
  if (c < Cc) {
    for (int i = ty; i < 32; i += 8)
      tile[i][tx] = in[(size_t)(r0 + i) * Cc + c];
  }
  __syncthreads();
  int r = r0 + tx;
  for (int i = ty; i < 32; i += 8) {
    int cc = c0 + i;
    if (cc < Cc)
      out[(size_t)cc * R + r] = f2bf(tile[tx][i]);
  }
}

// ---------------- masked row softmax attention (layer 1): one block per row ----------------
__global__ __launch_bounds__(256) void att_softmax_k(
    const unsigned* __restrict__ bits, const float* __restrict__ e1,
    const float* __restrict__ e2, float* __restrict__ att)
{
  __shared__ unsigned bw[256];
  __shared__ float red[4];
  int i = blockIdx.x, t = threadIdx.x;
  bw[t] = bits[(size_t)i * 256 + t];
  float e1i = e1[i];
  __syncthreads();
  float vv[32];
  float m = -3.4e38f;
#pragma unroll
  for (int it = 0; it < 32; ++it) {
    int j = t + it * 256;
    float e = e1i + e2[j];
    e = e > 0.f ? e : LRELU_ALPHA * e;
    bool on = (bw[j >> 5] >> (t & 31)) & 1;
    float v = on ? e : NEG_BIG;
    vv[it] = v;
    m = fmaxf(m, v);
  }
#pragma unroll
  for (int off = 32; off; off >>= 1) m = fmaxf(m, __shfl_xor(m, off));
  int w = t >> 6;
  if ((t & 63) == 0) red[w] = m;
  __syncthreads();
  m = fmaxf(fmaxf(red[0], red[1]), fmaxf(red[2], red[3]));
  __syncthreads();
  float s = 0.f;
#pragma unroll
  for (int it = 0; it < 32; ++it) {
    float p = __expf(vv[it] - m);
    vv[it] = p;
    s += p;
  }
#pragma unroll
  for (int off = 32; off; off >>= 1) s += __shfl_xor(s, off);
  if ((t & 63) == 0) red[w] = s;
  __syncthreads();
  s = red[0] + red[1] + red[2] + red[3];
  float inv = 1.f / s;
  float* orow = att + (size_t)i * 8192;
#pragma unroll
  for (int it = 0; it < 32; ++it)
    orow[t + it * 256] = vv[it] * inv;
}

// ---------------- MFMA bf16 GEMM (layer-1 aggregate): h1 = ELU(att1 @ Wh1) ----------------
// BM=BN=64, BK=64, 4 waves 2x2 (wave 32x32). Flat grid 512 with XCD-chunked
// swizzle: the 4 col-blocks of one A row-panel land on the SAME XCD -> A panel
// is fetched from HBM once and reused from that XCD's L2 (A traffic 1GB->256MB).
__global__ __launch_bounds__(256) void gemm_mfma1_k(
    const float* __restrict__ A, const unsigned short* __restrict__ BT,
    float* __restrict__ C)
{
  constexpr int BK = 64;
  __shared__ __align__(16) char As[64 * 128];
  __shared__ __align__(16) char Bs[64 * 128];
  int bid = blockIdx.x;
  int lid = ((bid & 7) << 6) | (bid >> 3);   // XCD-chunked remap (512 = 8*64)
  int col0 = (lid & 3) * 64;
  int row0 = (lid >> 2) * 64;
  int t = threadIdx.x;
  int w = t >> 6, l = t & 63;
  int wm = w >> 1, wn = w & 1;

  f32x4 acc[2][2] = {};

  int ar = t >> 2, aseg = t & 3;
  int swzA = (ar & 7) << 4;

  for (int kt = 0; kt < 128; ++kt) {
    __syncthreads();
    { // stage A (fp32 -> bf16, swizzled)
      const float4* src = (const float4*)(A + (size_t)(row0 + ar) * 8192 + kt * BK + aseg * 16);
      float4 v0 = src[0], v1 = src[1], v2 = src[2], v3 = src[3];
      u16x8 c0, c1;
      c0[0]=f2bf(v0.x); c0[1]=f2bf(v0.y); c0[2]=f2bf(v0.z); c0[3]=f2bf(v0.w);
      c0[4]=f2bf(v1.x); c0[5]=f2bf(v1.y); c0[6]=f2bf(v1.z); c0[7]=f2bf(v1.w);
      c1[0]=f2bf(v2.x); c1[1]=f2bf(v2.y); c1[2]=f2bf(v2.z); c1[3]=f2bf(v2.w);
      c1[4]=f2bf(v3.x); c1[5]=f2bf(v3.y); c1[6]=f2bf(v3.z); c1[7]=f2bf(v3.w);
      int base = ar * 128 + aseg * 32;
      *(u16x8*)(As + ((base) ^ swzA)) = c0;
      *(u16x8*)(As + ((base + 16) ^ swzA)) = c1;
    }
    { // stage B: 64 rows x 64 bf16
      int br = t >> 2, seg = t & 3;
      const u16x8* src = (const u16x8*)(BT + (size_t)(col0 + br) * 8192 + kt * BK + seg * 16);
      u16x8 b0 = src[0], b1 = src[1];
      int base = br * 128 + seg * 32;
      int swz = (br & 7) << 4;
      *(u16x8*)(Bs + ((base) ^ swz)) = b0;
      *(u16x8*)(Bs + ((base + 16) ^ swz)) = b1;
    }
    __syncthreads();
#pragma unroll
    for (int kk = 0; kk < BK; kk += 32) {
      bf16x8 af[2], bfr[2];
      int kb = (kk + (l >> 4) * 8) * 2;
#pragma unroll
      for (int fm = 0; fm < 2; ++fm) {
        int r = wm * 32 + fm * 16 + (l & 15);
        af[fm] = *(const bf16x8*)(As + ((r * 128 + kb) ^ ((r & 7) << 4)));
      }
#pragma unroll
      for (int fn = 0; fn < 2; ++fn) {
        int c = wn * 32 + fn * 16 + (l & 15);
        bfr[fn] = *(const bf16x8*)(Bs + ((c * 128 + kb) ^ ((c & 7) << 4)));
      }
#pragma unroll
      for (int fm = 0; fm < 2; ++fm)
#pragma unroll
        for (int fn = 0; fn < 2; ++fn)
          acc[fm][fn] = __builtin_amdgcn_mfma_f32_16x16x32_bf16(af[fm], bfr[fn], acc[fm][fn], 0, 0, 0);
    }
  }
  // epilogue: C/D layout col=lane&15, row=(lane>>4)*4+reg; ELU
#pragma unroll
  for (int fm = 0; fm < 2; ++fm) {
#pragma unroll
    for (int fn = 0; fn < 2; ++fn) {
#pragma unroll
      for (int r = 0; r < 4; ++r) {
        int grow = row0 + wm * 32 + fm * 16 + (l >> 4) * 4 + r;
        int gcol = col0 + wn * 32 + fn * 16 + (l & 15);
        float v = acc[fm][fn][r];
        v = v > 0.f ? v : expm1f(v);
        C[(size_t)grow * 256 + gcol] = v;
      }
    }
  }
}

// ---------------- small GEMM: Wh2[M][16] = h1[M][256] @ W2[256][16] ----------------
__global__ __launch_bounds__(256) void gemm_small_k(
    const float* __restrict__ A, const float* __restrict__ B,
    float* __restrict__ C, int K, int Ncols)
{
  int t = threadIdx.x;
  int r = blockIdx.x * 16 + (t >> 4);
  int c = t & 15;
  const float* arow = A + (size_t)r * K;
  float acc = 0.f;
#pragma unroll 8
  for (int k = 0; k < K; ++k)
    acc = fmaf(arow[k], B[k * Ncols + c], acc);
  C[(size_t)r * Ncols + c] = acc;
}

// ---------------- fused layer-2: masked softmax -> att2 write -> @Wh2 -> sigmoid ----------------
// 16 rows per block (512 blocks). Thread = (row-quad rq = t>>6, j-lane q = t&63).
// Each thread owns 4 rows x 128 j's; one Wh2 row read feeds 4 rows x 16 cols FMA.
// No max-shift: |e| <~ 5 for layer 2, exp stays in range; softmax invariant.
__global__ __launch_bounds__(256) void att_agg2_k(
    const unsigned* __restrict__ bits, const float* __restrict__ e1,
    const float* __restrict__ e2, const float* __restrict__ Wh2,
    float* __restrict__ att, float* __restrict__ out)
{
  __shared__ unsigned bwr[16][256];
  int i0 = blockIdx.x * 16;
  int t = threadIdx.x;
  int q = t & 63;
  int rq = t >> 6;
#pragma unroll
  for (int u = 0; u < 16; ++u) {
    int wdx = u * 256 + t;
    bwr[wdx >> 8][wdx & 255] = bits[(size_t)(i0 + (wdx >> 8)) * 256 + (wdx & 255)];
  }
  __syncthreads();
  float e1r[4];
#pragma unroll
  for (int rr = 0; rr < 4; ++rr) e1r[rr] = e1[i0 + rq * 4 + rr];

  // pass 1: row sums of exp(e) over unmasked
  float s[4] = {0.f, 0.f, 0.f, 0.f};
  for (int k = 0; k < 128; ++k) {
    int j = q + k * 64;
    float e2j = e2[j];
    int word = j >> 5, bit = q & 31;
#pragma unroll
    for (int rr = 0; rr < 4; ++rr) {
      float e = e1r[rr] + e2j;
      e = e > 0.f ? e : LRELU_ALPHA * e;
      unsigned wb = bwr[rq * 4 + rr][word];
      s[rr] += ((wb >> bit) & 1) ? __expf(e) : 0.f;
    }
  }
#pragma unroll
  for (int off = 32; off; off >>= 1)
#pragma unroll
    for (int rr = 0; rr < 4; ++rr) s[rr] += __shfl_xor(s[rr], off);
  float inv[4];
#pragma unroll
  for (int rr = 0; rr < 4; ++rr) inv[rr] = 1.f / s[rr];

  // pass 2: write att rows + accumulate h2
  float acc[4][16] = {};
  for (int k = 0; k < 128; ++k) {
    int j = q + k * 64;
    float e2j = e2[j];
    int word = j >> 5, bit = q & 31;
    const float4* wp = (const float4*)(Wh2 + (size_t)j * 16);
    float4 w0 = wp[0], w1 = wp[1], w2 = wp[2], w3 = wp[3];
#pragma unroll
    for (int rr = 0; rr < 4; ++rr) {
      float e = e1r[rr] + e2j;
      e = e > 0.f ? e : LRELU_ALPHA * e;
      unsigned wb = bwr[rq * 4 + rr][word];
      float p = ((wb >> bit) & 1) ? __expf(e) * inv[rr] : 0.f;
      att[(size_t)(i0 + rq * 4 + rr) * 8192 + j] = p;
      acc[rr][0]  = fmaf(p, w0.x, acc[rr][0]);
      acc[rr][1]  = fmaf(p, w0.y, acc[rr][1]);
      acc[rr][2]  = fmaf(p, w0.z, acc[rr][2]);
      acc[rr][3]  = fmaf(p, w0.w, acc[rr][3]);
      acc[rr][4]  = fmaf(p, w1.x, acc[rr][4]);
      acc[rr][5]  = fmaf(p, w1.y, acc[rr][5]);
      acc[rr][6]  = fmaf(p, w1.z, acc[rr][6]);
      acc[rr][7]  = fmaf(p, w1.w, acc[rr][7]);
      acc[rr][8]  = fmaf(p, w2.x, acc[rr][8]);
      acc[rr][9]  = fmaf(p, w2.y, acc[rr][9]);
      acc[rr][10] = fmaf(p, w2.z, acc[rr][10]);
      acc[rr][11] = fmaf(p, w2.w, acc[rr][11]);
      acc[rr][12] = fmaf(p, w3.x, acc[rr][12]);
      acc[rr][13] = fmaf(p, w3.y, acc[rr][13]);
      acc[rr][14] = fmaf(p, w3.z, acc[rr][14]);
      acc[rr][15] = fmaf(p, w3.w, acc[rr][15]);
    }
  }
#pragma unroll
  for (int off = 32; off; off >>= 1)
#pragma unroll
    for (int rr = 0; rr < 4; ++rr)
#pragma unroll
      for (int c = 0; c < 16; ++c)
        acc[rr][c] += __shfl_xor(acc[rr][c], off);
  if (q == 0) {
#pragma unroll
    for (int rr = 0; rr < 4; ++rr)
#pragma unroll
      for (int c = 0; c < 16; ++c)
        out[(size_t)(i0 + rq * 4 + rr) * 16 + c] = 1.f / (1.f + __expf(-acc[rr][c]));
  }
}

extern "C" void kernel_launch(void* const* d_in, const int* in_sizes, int n_in,
                              void* d_out, int out_size, void* d_ws, size_t ws_size,
                              hipStream_t stream)
{
  const float* x   = (const float*)d_in[0];
  const int*   adj = (const int*)d_in[1];
  const float* W1  = (const float*)d_in[2];
  const float* a1  = (const float*)d_in[3];
  const float* W2  = (const float*)d_in[4];
  const float* a2  = (const float*)d_in[5];

  float* out  = (float*)d_out;                 // [8192*16]
  float* h1   = out + 131072;                  // [8192*256]
  float* att1 = h1 + 2097152;                  // [8192*8192]
  float* att2 = att1 + 67108864;               // [8192*8192]

  float* ws = (float*)d_ws;
  float* wh1 = ws;                                            // 2097152 f
  unsigned short* bt1 = (unsigned short*)(wh1 + 2097152);     // 2097152 u16
  float* e1a = wh1 + 2097152 + 1048576;
  float* e2a = e1a + 8192;
  float* wh2 = e2a + 8192;                                    // 131072 f
  float* e1b = wh2 + 131072;
  float* e2b = e1b + 8192;
  unsigned* bits = (unsigned*)(e2b + 8192);                   // 8192*256 u32

  pack_adj_k<<<8192, 256, 0, stream>>>(adj, bits);

  // ---- layer 1 ----
  gemm_f32_k<<<dim3(64, 4), 256, 0, stream>>>(x, W1, wh1, 8192, 512, 256);
  calc_e_k<<<2048, 256, 0, stream>>>(wh1, a1, e1a, e2a, 256);
  transpose_bf16_k<<<dim3(8, 256), dim3(32, 8), 0, stream>>>(wh1, bt1, 8192, 256);
  att_softmax_k<<<8192, 256, 0, stream>>>(bits, e1a, e2a, att1);
  gemm_mfma1_k<<<512, 256, 0, stream>>>(att1, bt1, h1);

  // ---- layer 2 ----
  gemm_small_k<<<512, 256, 0, stream>>>(h1, W2, wh2, 256, 16);
  calc_e_k<<<2048, 256, 0, stream>>>(wh2, a2, e1b, e2b, 16);
  att_agg2_k<<<512, 256, 0, stream>>>(bits, e1b, e2b, wh2, att2, out);
}

// Round 3
// 559.128 us; speedup vs baseline: 1.0304x; 1.0304x over previous
//
#include <hip/hip_runtime.h>
#include <hip/hip_bf16.h>

#define LRELU_ALPHA 0.2f

typedef __attribute__((ext_vector_type(8))) __bf16 bf16x8;
typedef __attribute__((ext_vector_type(4))) float f32x4;
typedef __attribute__((ext_vector_type(8))) unsigned short u16x8;
typedef __attribute__((ext_vector_type(4))) unsigned short u16x4;

__device__ __forceinline__ unsigned short f2bf(float f) {
  unsigned int u = __float_as_uint(f);
  u += 0x7fffu + ((u >> 16) & 1u);   // round-to-nearest-even
  return (unsigned short)(u >> 16);
}

// ---------------- adj bit-pack: bits[i][w] = 32 adjacency bits ----------------
__global__ __launch_bounds__(256) void pack_adj_k(
    const int* __restrict__ adj, unsigned* __restrict__ bits)
{
  size_t i = blockIdx.x;
  const int* arow = adj + i * 8192;
  unsigned* brow = bits + i * 256;
  int t = threadIdx.x;
  int l = t & 63;
#pragma unroll
  for (int it = 0; it < 32; ++it) {
    int j = it * 256 + t;
    unsigned long long m = __ballot(arow[j] > 0);
    if (l == 0) brow[j >> 5] = (unsigned)m;
    else if (l == 32) brow[j >> 5] = (unsigned)(m >> 32);
  }
}

// ---------------- fp32 tiled GEMM: C[M][Nc] = A[M][K] @ B[K][Nc] ----------------
__global__ __launch_bounds__(256) void gemm_f32_k(
    const float* __restrict__ A, const float* __restrict__ B,
    float* __restrict__ C, int M, int K, int Ncols)
{
  __shared__ float As[128][17];
  __shared__ float Bs[16][65];
  int t = threadIdx.x;
  int row0 = blockIdx.x * 128;
  int col0 = blockIdx.y * 64;
  int ty = t >> 4, tx = t & 15;
  float acc[8][4];
#pragma unroll
  for (int i = 0; i < 8; ++i)
#pragma unroll
    for (int j = 0; j < 4; ++j) acc[i][j] = 0.f;

  for (int kt = 0; kt < K; kt += 16) {
    __syncthreads();
    {
      int r = t >> 1, h = t & 1;
      const float4* src = (const float4*)(A + (size_t)(row0 + r) * K + kt + h * 8);
      float4 v0 = src[0], v1 = src[1];
      float* dst = &As[r][h * 8];
      dst[0]=v0.x; dst[1]=v0.y; dst[2]=v0.z; dst[3]=v0.w;
      dst[4]=v1.x; dst[5]=v1.y; dst[6]=v1.z; dst[7]=v1.w;
    }
    {
      int kr = t >> 4, seg = t & 15;
      const float4* src = (const float4*)(B + (size_t)(kt + kr) * Ncols + col0 + seg * 4);
      float4 v = src[0];
      float* dst = &Bs[kr][seg * 4];
      dst[0]=v.x; dst[1]=v.y; dst[2]=v.z; dst[3]=v.w;
    }
    __syncthreads();
#pragma unroll
    for (int k = 0; k < 16; ++k) {
      float bb[4];
#pragma unroll
      for (int j = 0; j < 4; ++j) bb[j] = Bs[k][tx * 4 + j];
#pragma unroll
      for (int i = 0; i < 8; ++i) {
        float aa = As[ty * 8 + i][k];
#pragma unroll
        for (int j = 0; j < 4; ++j) acc[i][j] = fmaf(aa, bb[j], acc[i][j]);
      }
    }
  }
#pragma unroll
  for (int i = 0; i < 8; ++i) {
    float4 v = make_float4(acc[i][0], acc[i][1], acc[i][2], acc[i][3]);
    *(float4*)(C + (size_t)(row0 + ty * 8 + i) * Ncols + col0 + tx * 4) = v;
  }
}

// ---------------- e1/e2 vectors: wave per row ----------------
__global__ __launch_bounds__(256) void calc_e_k(
    const float* __restrict__ Wh, const float* __restrict__ a,
    float* __restrict__ e1, float* __restrict__ e2, int F)
{
  int row = blockIdx.x * 4 + (threadIdx.x >> 6);
  int l = threadIdx.x & 63;
  const float* r = Wh + (size_t)row * F;
  float s1 = 0.f, s2 = 0.f;
  for (int f = l; f < F; f += 64) {
    float v = r[f];
    s1 += v * a[f];
    s2 += v * a[F + f];
  }
#pragma unroll
  for (int off = 32; off; off >>= 1) {
    s1 += __shfl_down(s1, off);
    s2 += __shfl_down(s2, off);
  }
  if (l == 0) { e1[row] = s1; e2[row] = s2; }
}

// ---------------- transpose + fp32->bf16: out[c][r] = bf16(in[r][c]) ----------------
__global__ void transpose_bf16_k(const float* __restrict__ in, unsigned short* __restrict__ out,
                                 int R, int Cc)
{
  __shared__ float tile[32][33];
  int tx = threadIdx.x, ty = threadIdx.y;
  int c0 = blockIdx.x * 32, r0 = blockIdx.y * 32;
  int c = c0 + tx;
  if (c < Cc) {
    for (int i = ty; i < 32; i += 8)
      tile[i][tx] = in[(size_t)(r0 + i) * Cc + c];
  }
  __syncthreads();
  int r = r0 + tx;
  for (int i = ty; i < 32; i += 8) {
    int cc = c0 + i;
    if (cc < Cc)
      out[(size_t)cc * R + r] = f2bf(tile[tx][i]);
  }
}

// ---------------- masked row softmax: one block per row, dual fp32+bf16 write ----------------
// No max-shift: masked entries are exact 0.0; |e| <= ~14 so exp() is fp32-safe;
// softmax is shift-invariant -> identical result after normalization.
__global__ __launch_bounds__(256) void att_softmax_k(
    const unsigned* __restrict__ bits, const float* __restrict__ e1,
    const float* __restrict__ e2, float* __restrict__ att,
    unsigned short* __restrict__ attb)
{
  __shared__ unsigned bw[256];
  __shared__ float red[4];
  int i = blockIdx.x, t = threadIdx.x;
  bw[t] = bits[(size_t)i * 256 + t];
  float e1i = e1[i];
  __syncthreads();
  float vv[32];
  float s = 0.f;
#pragma unroll
  for (int it = 0; it < 32; ++it) {
    int j = t + it * 256;
    float e = e1i + e2[j];
    e = e > 0.f ? e : LRELU_ALPHA * e;
    bool on = (bw[j >> 5] >> (t & 31)) & 1;
    float p = on ? __expf(e) : 0.f;
    vv[it] = p;
    s += p;
  }
#pragma unroll
  for (int off = 32; off; off >>= 1) s += __shfl_xor(s, off);
  if ((t & 63) == 0) red[t >> 6] = s;
  __syncthreads();
  s = red[0] + red[1] + red[2] + red[3];
  float inv = 1.f / s;
  float* orow = att + (size_t)i * 8192;
  unsigned short* obrow = attb + (size_t)i * 8192;
#pragma unroll
  for (int it = 0; it < 32; ++it) {
    int j = t + it * 256;
    float p = vv[it] * inv;
    orow[j] = p;
    obrow[j] = f2bf(p);
  }
}

// ---------------- MFMA bf16 GEMM: C = epi(A_bf16[M][K] @ BT_bf16[Nc][K]^T) ----------------
// BM=128, BK=64, 4 waves. BN=64: waves 2x2 (wave 64x32, FM=4,FN=2).
// BN=16: waves 4x1 (wave 32x16, FM=2,FN=1). Register-prefetch of tile k+1
// issued between barriers so global latency hides under ds_read+MFMA.
template<int BN, int SPLITK, int EPI>
__global__ __launch_bounds__(256) void gemm_mfma_k(
    const unsigned short* __restrict__ A, const unsigned short* __restrict__ BT,
    float* __restrict__ Cout, int M, int K, int ldc)
{
  constexpr int BM = 128, BK = 64;
  constexpr int WN = (BN == 64) ? 2 : 1;
  constexpr int WM = 4 / WN;
  constexpr int WROWS = BM / WM;   // 64 or 32
  constexpr int WCOLS = BN / WN;   // 32 or 16
  constexpr int FM = WROWS / 16;   // 4 or 2
  constexpr int FN = WCOLS / 16;   // 2 or 1
  __shared__ __align__(16) char As[BM * 128];
  __shared__ __align__(16) char Bs[BN * 128];
  int t = threadIdx.x;
  int row0 = blockIdx.x * BM;
  int col0 = blockIdx.y * BN;
  int nt = K / BK / SPLITK;
  int w = t >> 6, l = t & 63;
  int wm = w / WN, wn = w % WN;

  f32x4 acc[FM][FN] = {};

  int ar = t >> 1, aco = (t & 1) * 32;          // A: 2 threads/row, 32 elems each
  int swzA = (ar & 7) << 4;
  int abase = ar * 128 + aco * 2;

  int br, bco;
  if constexpr (BN == 64) { br = t >> 2; bco = (t & 3) * 16; }
  else                    { br = t >> 4; bco = (t & 15) * 4; }
  int swzB = (br & 7) << 4;
  int bbase = br * 128 + bco * 2;

  const unsigned short* agp = A + (size_t)(row0 + ar) * K + (size_t)blockIdx.z * nt * BK + aco;
  const unsigned short* bgp = BT + (size_t)(col0 + br) * K + (size_t)blockIdx.z * nt * BK + bco;

  u16x8 pa0, pa1, pa2, pa3, pb0, pb1;
  u16x4 pbs;
  pa0 = *(const u16x8*)(agp + 0);
  pa1 = *(const u16x8*)(agp + 8);
  pa2 = *(const u16x8*)(agp + 16);
  pa3 = *(const u16x8*)(agp + 24);
  if constexpr (BN == 64) {
    pb0 = *(const u16x8*)(bgp + 0);
    pb1 = *(const u16x8*)(bgp + 8);
  } else {
    pbs = *(const u16x4*)(bgp + 0);
  }

  for (int kt = 0; kt < nt; ++kt) {
    __syncthreads();
    *(u16x8*)(As + ((abase +  0) ^ swzA)) = pa0;
    *(u16x8*)(As + ((abase + 16) ^ swzA)) = pa1;
    *(u16x8*)(As + ((abase + 32) ^ swzA)) = pa2;
    *(u16x8*)(As + ((abase + 48) ^ swzA)) = pa3;
    if constexpr (BN == 64) {
      *(u16x8*)(Bs + ((bbase +  0) ^ swzB)) = pb0;
      *(u16x8*)(Bs + ((bbase + 16) ^ swzB)) = pb1;
    } else {
      *(u16x4*)(Bs + (bbase ^ swzB)) = pbs;
    }
    __syncthreads();
    if (kt + 1 < nt) {
      const unsigned short* ag = agp + (kt + 1) * BK;
      const unsigned short* bg = bgp + (kt + 1) * BK;
      pa0 = *(const u16x8*)(ag + 0);
      pa1 = *(const u16x8*)(ag + 8);
      pa2 = *(const u16x8*)(ag + 16);
      pa3 = *(const u16x8*)(ag + 24);
      if constexpr (BN == 64) {
        pb0 = *(const u16x8*)(bg + 0);
        pb1 = *(const u16x8*)(bg + 8);
      } else {
        pbs = *(const u16x4*)(bg + 0);
      }
    }
#pragma unroll
    for (int kk = 0; kk < BK; kk += 32) {
      bf16x8 af[FM], bfr[FN];
      int kb = (kk + (l >> 4) * 8) * 2;
#pragma unroll
      for (int fm = 0; fm < FM; ++fm) {
        int r = wm * WROWS + fm * 16 + (l & 15);
        af[fm] = *(const bf16x8*)(As + ((r * 128 + kb) ^ ((r & 7) << 4)));
      }
#pragma unroll
      for (int fn = 0; fn < FN; ++fn) {
        int c = wn * WCOLS + fn * 16 + (l & 15);
        bfr[fn] = *(const bf16x8*)(Bs + ((c * 128 + kb) ^ ((c & 7) << 4)));
      }
#pragma unroll
      for (int fm = 0; fm < FM; ++fm)
#pragma unroll
        for (int fn = 0; fn < FN; ++fn)
          acc[fm][fn] = __builtin_amdgcn_mfma_f32_16x16x32_bf16(af[fm], bfr[fn], acc[fm][fn], 0, 0, 0);
    }
  }
  // epilogue: C/D layout col=lane&15, row=(lane>>4)*4+reg
#pragma unroll
  for (int fm = 0; fm < FM; ++fm) {
#pragma unroll
    for (int fn = 0; fn < FN; ++fn) {
#pragma unroll
      for (int r = 0; r < 4; ++r) {
        int grow = row0 + wm * WROWS + fm * 16 + (l >> 4) * 4 + r;
        int gcol = col0 + wn * WCOLS + fn * 16 + (l & 15);
        float v = acc[fm][fn][r];
        if constexpr (EPI == 1) v = v > 0.f ? v : expm1f(v);   // ELU alpha=1
        size_t idx = (SPLITK > 1)
          ? ((size_t)blockIdx.z * M + grow) * ldc + gcol
          : (size_t)grow * ldc + gcol;
        Cout[idx] = v;
      }
    }
  }
}

// ---------------- small GEMM: Wh2[M][16] = h1[M][256] @ W2[256][16] ----------------
__global__ __launch_bounds__(256) void gemm_small_k(
    const float* __restrict__ A, const float* __restrict__ B,
    float* __restrict__ C, int K, int Ncols)
{
  int t = threadIdx.x;
  int r = blockIdx.x * 16 + (t >> 4);
  int c = t & 15;
  const float* arow = A + (size_t)r * K;
  float acc = 0.f;
#pragma unroll 8
  for (int k = 0; k < K; ++k)
    acc = fmaf(arow[k], B[k * Ncols + c], acc);
  C[(size_t)r * Ncols + c] = acc;
}

// ---------------- split-K reduce + sigmoid ----------------
__global__ void reduce_sig_k(const float* __restrict__ part, float* __restrict__ out, int total)
{
  int i = blockIdx.x * 256 + threadIdx.x;
  if (i < total) {
    float s = part[i] + part[total + i] + part[2 * (size_t)total + i] + part[3 * (size_t)total + i];
    out[i] = 1.f / (1.f + __expf(-s));
  }
}

extern "C" void kernel_launch(void* const* d_in, const int* in_sizes, int n_in,
                              void* d_out, int out_size, void* d_ws, size_t ws_size,
                              hipStream_t stream)
{
  const float* x   = (const float*)d_in[0];
  const int*   adj = (const int*)d_in[1];
  const float* W1  = (const float*)d_in[2];
  const float* a1  = (const float*)d_in[3];
  const float* W2  = (const float*)d_in[4];
  const float* a2  = (const float*)d_in[5];

  float* out  = (float*)d_out;                 // [8192*16]
  float* h1   = out + 131072;                  // [8192*256]
  float* att1 = h1 + 2097152;                  // [8192*8192]
  float* att2 = att1 + 67108864;               // [8192*8192]

  float* ws = (float*)d_ws;
  float* wh1 = ws;                                            // 2097152 f
  unsigned short* bt1 = (unsigned short*)(wh1 + 2097152);     // 2097152 u16
  float* e1a = wh1 + 2097152 + 1048576;
  float* e2a = e1a + 8192;
  float* wh2 = e2a + 8192;                                    // 131072 f
  unsigned short* bt2 = (unsigned short*)(wh2 + 131072);      // 131072 u16
  float* e1b = wh2 + 131072 + 65536;
  float* e2b = e1b + 8192;
  unsigned* bits = (unsigned*)(e2b + 8192);                   // 2097152 u32
  float* part = (float*)(bits + 2097152);                     // 524288 f
  unsigned short* att1b = (unsigned short*)(part + 524288);   // 67108864 u16
  unsigned short* att2b = att1b + 67108864;                   // 67108864 u16

  pack_adj_k<<<8192, 256, 0, stream>>>(adj, bits);

  // ---- layer 1 ----
  gemm_f32_k<<<dim3(64, 4), 256, 0, stream>>>(x, W1, wh1, 8192, 512, 256);
  calc_e_k<<<2048, 256, 0, stream>>>(wh1, a1, e1a, e2a, 256);
  transpose_bf16_k<<<dim3(8, 256), dim3(32, 8), 0, stream>>>(wh1, bt1, 8192, 256);
  att_softmax_k<<<8192, 256, 0, stream>>>(bits, e1a, e2a, att1, att1b);
  gemm_mfma_k<64, 1, 1><<<dim3(64, 4, 1), 256, 0, stream>>>(att1b, bt1, h1, 8192, 8192, 256);

  // ---- layer 2 ----
  gemm_small_k<<<512, 256, 0, stream>>>(h1, W2, wh2, 256, 16);
  calc_e_k<<<2048, 256, 0, stream>>>(wh2, a2, e1b, e2b, 16);
  transpose_bf16_k<<<dim3(1, 256), dim3(32, 8), 0, stream>>>(wh2, bt2, 8192, 16);
  att_softmax_k<<<8192, 256, 0, stream>>>(bits, e1b, e2b, att2, att2b);
  gemm_mfma_k<16, 4, 0><<<dim3(64, 1, 4), 256, 0, stream>>>(att2b, bt2, part, 8192, 8192, 16);
  reduce_sig_k<<<512, 256, 0, stream>>>(part, out, 131072);
}

// Round 4
// 555.104 us; speedup vs baseline: 1.0379x; 1.0073x over previous
//
#include <hip/hip_runtime.h>
#include <hip/hip_bf16.h>

#define LRELU_ALPHA 0.2f

typedef __attribute__((ext_vector_type(8))) __bf16 bf16x8;
typedef __attribute__((ext_vector_type(4))) float f32x4;
typedef __attribute__((ext_vector_type(8))) unsigned short u16x8;
typedef __attribute__((ext_vector_type(4))) unsigned short u16x4;

__device__ __forceinline__ unsigned short f2bf(float f) {
  unsigned int u = __float_as_uint(f);
  u += 0x7fffu + ((u >> 16) & 1u);   // round-to-nearest-even
  return (unsigned short)(u >> 16);
}

// ---------------- adj bit-pack: bits[i][w] = 32 adjacency bits ----------------
__global__ __launch_bounds__(256) void pack_adj_k(
    const int* __restrict__ adj, unsigned* __restrict__ bits)
{
  size_t i = blockIdx.x;
  const int* arow = adj + i * 8192;
  unsigned* brow = bits + i * 256;
  int t = threadIdx.x;
  int l = t & 63;
#pragma unroll
  for (int it = 0; it < 32; ++it) {
    int j = it * 256 + t;
    unsigned long long m = __ballot(arow[j] > 0);
    if (l == 0) brow[j >> 5] = (unsigned)m;
    else if (l == 32) brow[j >> 5] = (unsigned)(m >> 32);
  }
}

// ---------------- fp32 tiled GEMM: C[M][Nc] = A[M][K] @ B[K][Nc] ----------------
__global__ __launch_bounds__(256) void gemm_f32_k(
    const float* __restrict__ A, const float* __restrict__ B,
    float* __restrict__ C, int M, int K, int Ncols)
{
  __shared__ float As[128][17];
  __shared__ float Bs[16][65];
  int t = threadIdx.x;
  int row0 = blockIdx.x * 128;
  int col0 = blockIdx.y * 64;
  int ty = t >> 4, tx = t & 15;
  float acc[8][4];
#pragma unroll
  for (int i = 0; i < 8; ++i)
#pragma unroll
    for (int j = 0; j < 4; ++j) acc[i][j] = 0.f;

  for (int kt = 0; kt < K; kt += 16) {
    __syncthreads();
    {
      int r = t >> 1, h = t & 1;
      const float4* src = (const float4*)(A + (size_t)(row0 + r) * K + kt + h * 8);
      float4 v0 = src[0], v1 = src[1];
      float* dst = &As[r][h * 8];
      dst[0]=v0.x; dst[1]=v0.y; dst[2]=v0.z; dst[3]=v0.w;
      dst[4]=v1.x; dst[5]=v1.y; dst[6]=v1.z; dst[7]=v1.w;
    }
    {
      int kr = t >> 4, seg = t & 15;
      const float4* src = (const float4*)(B + (size_t)(kt + kr) * Ncols + col0 + seg * 4);
      float4 v = src[0];
      float* dst = &Bs[kr][seg * 4];
      dst[0]=v.x; dst[1]=v.y; dst[2]=v.z; dst[3]=v.w;
    }
    __syncthreads();
#pragma unroll
    for (int k = 0; k < 16; ++k) {
      float bb[4];
#pragma unroll
      for (int j = 0; j < 4; ++j) bb[j] = Bs[k][tx * 4 + j];
#pragma unroll
      for (int i = 0; i < 8; ++i) {
        float aa = As[ty * 8 + i][k];
#pragma unroll
        for (int j = 0; j < 4; ++j) acc[i][j] = fmaf(aa, bb[j], acc[i][j]);
      }
    }
  }
#pragma unroll
  for (int i = 0; i < 8; ++i) {
    float4 v = make_float4(acc[i][0], acc[i][1], acc[i][2], acc[i][3]);
    *(float4*)(C + (size_t)(row0 + ty * 8 + i) * Ncols + col0 + tx * 4) = v;
  }
}

// ---------------- e1/e2 vectors: wave per row ----------------
__global__ __launch_bounds__(256) void calc_e_k(
    const float* __restrict__ Wh, const float* __restrict__ a,
    float* __restrict__ e1, float* __restrict__ e2, int F)
{
  int row = blockIdx.x * 4 + (threadIdx.x >> 6);
  int l = threadIdx.x & 63;
  const float* r = Wh + (size_t)row * F;
  float s1 = 0.f, s2 = 0.f;
  for (int f = l; f < F; f += 64) {
    float v = r[f];
    s1 += v * a[f];
    s2 += v * a[F + f];
  }
#pragma unroll
  for (int off = 32; off; off >>= 1) {
    s1 += __shfl_down(s1, off);
    s2 += __shfl_down(s2, off);
  }
  if (l == 0) { e1[row] = s1; e2[row] = s2; }
}

// ---------------- transpose + fp32->bf16: out[c][r] = bf16(in[r][c]) ----------------
__global__ void transpose_bf16_k(const float* __restrict__ in, unsigned short* __restrict__ out,
                                 int R, int Cc)
{
  __shared__ float tile[32][33];
  int tx = threadIdx.x, ty = threadIdx.y;
  int c0 = blockIdx.x * 32, r0 = blockIdx.y * 32;
  int c = c0 + tx;
  if (c < Cc) {
    for (int i = ty; i < 32; i += 8)
      tile[i][tx] = in[(size_t)(r0 + i) * Cc + c];
  }
  __syncthreads();
  int r = r0 + tx;
  for (int i = ty; i < 32; i += 8) {
    int cc = c0 + i;
    if (cc < 16 || cc < Cc)
      if (cc < Cc)
        out[(size_t)cc * R + r] = f2bf(tile[tx][i]);
  }
}

// ---------------- row denominators: sinv[i] = 1 / sum_j mask*exp(lrelu(e1+e2)) ----------------
// No max-shift: e <= ~14 -> exp <= 1.2e6, sum <= 1e10, fp32-safe; softmax shift-invariant.
__global__ __launch_bounds__(256) void rowsum_k(
    const unsigned* __restrict__ bits, const float* __restrict__ e1,
    const float* __restrict__ e2, float* __restrict__ sinv)
{
  int gr = blockIdx.x * 4 + (threadIdx.x >> 6);
  int l = threadIdx.x & 63;
  float e1r = e1[gr];
  const unsigned* brow = bits + (size_t)gr * 256;
  float s = 0.f;
  for (int it = 0; it < 128; ++it) {
    unsigned bwv = brow[it * 2 + (l >> 5)];
    float e = e1r + e2[it * 64 + l];
    e = e > 0.f ? e : LRELU_ALPHA * e;
    s += ((bwv >> (l & 31)) & 1) ? __expf(e) : 0.f;
  }
#pragma unroll
  for (int off = 32; off; off >>= 1) s += __shfl_xor(s, off);
  if (l == 0) sinv[gr] = 1.f / s;
}

// ---------------- fused layer 1: p = softmax row (att1 write) + MFMA p@Wh1 -> ELU h1 ----------------
// 256 blocks x 512 thr. Block = 32 rows x full 256 cols. Per j-tile(64): compute p
// in regs (exp * precomputed sinv), write att fp32 once, drop bf16 p into swizzled
// LDS, MFMA against LDS-staged bt1 panel (bt1 = 4MB, L2-resident).
__global__ __launch_bounds__(512) void fused_att_agg1_k(
    const unsigned* __restrict__ bits, const float* __restrict__ e1,
    const float* __restrict__ e2, const float* __restrict__ sinv,
    const unsigned short* __restrict__ BT,   // bt1 [256][8192]
    float* __restrict__ att, float* __restrict__ h1)
{
  __shared__ __align__(16) char Ps[32 * 128];    // p tile bf16 [32 r][64 j] swizzled
  __shared__ __align__(16) char Bs[256 * 128];   // B tile bf16 [256 c][64 j] swizzled
  int t = threadIdx.x;
  int l = t & 63, w = t >> 6;          // 8 waves
  int row0 = blockIdx.x * 32;
  int rg = w >> 2, cg = w & 3;         // MFMA: row-group(16) x col-group(64)

  int pr0 = w * 4;                     // p-compute rows pr0..pr0+3
  float e1s[4], siv[4];
#pragma unroll
  for (int rr = 0; rr < 4; ++rr) {
    e1s[rr] = e1[row0 + pr0 + rr];
    siv[rr] = sinv[row0 + pr0 + rr];
  }

  int sc = t >> 1, sh = t & 1;         // B staging: col sc, half sh (32 elems)
  const unsigned short* bgp = BT + (size_t)sc * 8192 + sh * 32;
  int bbase = sc * 128 + sh * 64;
  int bswz = (sc & 7) << 4;

  f32x4 acc[4] = {};

  // prefetch tile 0
  float e2v = e2[l];
  unsigned bw[4];
#pragma unroll
  for (int rr = 0; rr < 4; ++rr)
    bw[rr] = bits[(size_t)(row0 + pr0 + rr) * 256 + (l >> 5)];
  u16x8 pb[4];
#pragma unroll
  for (int s = 0; s < 4; ++s) pb[s] = *(const u16x8*)(bgp + s * 8);

  for (int kt = 0; kt < 128; ++kt) {
    __syncthreads();
#pragma unroll
    for (int s = 0; s < 4; ++s)
      *(u16x8*)(Bs + ((bbase + s * 16) ^ bswz)) = pb[s];
    int j = kt * 64 + l;
#pragma unroll
    for (int rr = 0; rr < 4; ++rr) {
      float e = e1s[rr] + e2v;
      e = e > 0.f ? e : LRELU_ALPHA * e;
      float p = ((bw[rr] >> (l & 31)) & 1) ? __expf(e) * siv[rr] : 0.f;
      att[(size_t)(row0 + pr0 + rr) * 8192 + j] = p;
      int r = pr0 + rr;
      *(unsigned short*)(Ps + ((r * 128 + l * 2) ^ ((r & 7) << 4))) = f2bf(p);
    }
    __syncthreads();
    if (kt < 127) {
      e2v = e2[(kt + 1) * 64 + l];
#pragma unroll
      for (int rr = 0; rr < 4; ++rr)
        bw[rr] = bits[(size_t)(row0 + pr0 + rr) * 256 + (kt + 1) * 2 + (l >> 5)];
#pragma unroll
      for (int s = 0; s < 4; ++s)
        pb[s] = *(const u16x8*)(bgp + (kt + 1) * 64 + s * 8);
    }
#pragma unroll
    for (int kk = 0; kk < 64; kk += 32) {
      int kb = (kk + (l >> 4) * 8) * 2;
      int r = rg * 16 + (l & 15);
      bf16x8 af = *(const bf16x8*)(Ps + ((r * 128 + kb) ^ ((r & 7) << 4)));
#pragma unroll
      for (int fn = 0; fn < 4; ++fn) {
        int c = cg * 64 + fn * 16 + (l & 15);
        bf16x8 bf = *(const bf16x8*)(Bs + ((c * 128 + kb) ^ ((c & 7) << 4)));
        acc[fn] = __builtin_amdgcn_mfma_f32_16x16x32_bf16(af, bf, acc[fn], 0, 0, 0);
      }
    }
  }
  // epilogue: ELU -> h1. C/D: col=lane&15, row=(lane>>4)*4+reg
#pragma unroll
  for (int fn = 0; fn < 4; ++fn) {
#pragma unroll
    for (int r = 0; r < 4; ++r) {
      int grow = row0 + rg * 16 + (l >> 4) * 4 + r;
      int gcol = cg * 64 + fn * 16 + (l & 15);
      float v = acc[fn][r];
      v = v > 0.f ? v : expm1f(v);
      h1[(size_t)grow * 256 + gcol] = v;
    }
  }
}

// ---------------- small GEMM: Wh2[M][16] = h1[M][256] @ W2[256][16] ----------------
__global__ __launch_bounds__(256) void gemm_small_k(
    const float* __restrict__ A, const float* __restrict__ B,
    float* __restrict__ C, int K, int Ncols)
{
  int t = threadIdx.x;
  int r = blockIdx.x * 16 + (t >> 4);
  int c = t & 15;
  const float* arow = A + (size_t)r * K;
  float acc = 0.f;
#pragma unroll 8
  for (int k = 0; k < K; ++k)
    acc = fmaf(arow[k], B[k * Ncols + c], acc);
  C[(size_t)r * Ncols + c] = acc;
}

// ---------------- fused layer 2: p (att2 write) + MFMA p@Wh2 -> sigmoid out ----------------
// 256 blocks x 512 thr, 32 rows/block, BN=16. Waves 0-3 MFMA (rg=w&1 rows,
// ks=w>>1 j-half of each tile); all 8 waves do p-compute + staging.
__global__ __launch_bounds__(512) void fused_att_agg2_k(
    const unsigned* __restrict__ bits, const float* __restrict__ e1,
    const float* __restrict__ e2, const float* __restrict__ sinv,
    const unsigned short* __restrict__ BT,   // bt2 [16][8192]
    float* __restrict__ att, float* __restrict__ out)
{
  __shared__ __align__(16) char Ps[32 * 128];   // [32 r][64 j] bf16 swz
  __shared__ __align__(16) char Bs[16 * 128];   // [16 c][64 j] bf16 swz
  __shared__ float red[2][64][4];
  int t = threadIdx.x;
  int l = t & 63, w = t >> 6;
  int row0 = blockIdx.x * 32;
  int rg = w & 1, ks = w >> 1;         // valid for w<4

  int pr0 = w * 4;
  float e1s[4], siv[4];
#pragma unroll
  for (int rr = 0; rr < 4; ++rr) {
    e1s[rr] = e1[row0 + pr0 + rr];
    siv[rr] = sinv[row0 + pr0 + rr];
  }

  int sc = t >> 4, seg = t & 15;       // t<256: col sc(0..15), 4 elems
  const unsigned short* bgp = BT + (size_t)sc * 8192 + seg * 4;
  int bbase = sc * 128 + seg * 8;
  int bswz = (sc & 7) << 4;

  f32x4 acc = {};

  float e2v = e2[l];
  unsigned bw[4];
#pragma unroll
  for (int rr = 0; rr < 4; ++rr)
    bw[rr] = bits[(size_t)(row0 + pr0 + rr) * 256 + (l >> 5)];
  u16x4 pbs;
  if (t < 256) pbs = *(const u16x4*)(bgp);

  for (int kt = 0; kt < 128; ++kt) {
    __syncthreads();
    if (t < 256) *(u16x4*)(Bs + (bbase ^ bswz)) = pbs;
    int j = kt * 64 + l;
#pragma unroll
    for (int rr = 0; rr < 4; ++rr) {
      float e = e1s[rr] + e2v;
      e = e > 0.f ? e : LRELU_ALPHA * e;
      float p = ((bw[rr] >> (l & 31)) & 1) ? __expf(e) * siv[rr] : 0.f;
      att[(size_t)(row0 + pr0 + rr) * 8192 + j] = p;
      int r = pr0 + rr;
      *(unsigned short*)(Ps + ((r * 128 + l * 2) ^ ((r & 7) << 4))) = f2bf(p);
    }
    __syncthreads();
    if (kt < 127) {
      e2v = e2[(kt + 1) * 64 + l];
#pragma unroll
      for (int rr = 0; rr < 4; ++rr)
        bw[rr] = bits[(size_t)(row0 + pr0 + rr) * 256 + (kt + 1) * 2 + (l >> 5)];
      if (t < 256) pbs = *(const u16x4*)(bgp + (kt + 1) * 64);
    }
    if (w < 4) {
      int kb = (ks * 32 + (l >> 4) * 8) * 2;
      int r = rg * 16 + (l & 15);
      bf16x8 af = *(const bf16x8*)(Ps + ((r * 128 + kb) ^ ((r & 7) << 4)));
      int c = l & 15;
      bf16x8 bf = *(const bf16x8*)(Bs + ((c * 128 + kb) ^ ((c & 7) << 4)));
      acc = __builtin_amdgcn_mfma_f32_16x16x32_bf16(af, bf, acc, 0, 0, 0);
    }
  }
  // reduce ks=1 into ks=0, sigmoid, write out
  if (w >= 2 && w < 4) {
#pragma unroll
    for (int r = 0; r < 4; ++r) red[w - 2][l][r] = acc[r];
  }
  __syncthreads();
  if (w < 2) {
#pragma unroll
    for (int r = 0; r < 4; ++r) {
      float v = acc[r] + red[w][l][r];
      int grow = row0 + rg * 16 + (l >> 4) * 4 + r;
      int gcol = l & 15;
      out[(size_t)grow * 16 + gcol] = 1.f / (1.f + __expf(-v));
    }
  }
}

extern "C" void kernel_launch(void* const* d_in, const int* in_sizes, int n_in,
                              void* d_out, int out_size, void* d_ws, size_t ws_size,
                              hipStream_t stream)
{
  const float* x   = (const float*)d_in[0];
  const int*   adj = (const int*)d_in[1];
  const float* W1  = (const float*)d_in[2];
  const float* a1  = (const float*)d_in[3];
  const float* W2  = (const float*)d_in[4];
  const float* a2  = (const float*)d_in[5];

  float* out  = (float*)d_out;                 // [8192*16]
  float* h1   = out + 131072;                  // [8192*256]
  float* att1 = h1 + 2097152;                  // [8192*8192]
  float* att2 = att1 + 67108864;               // [8192*8192]

  float* ws = (float*)d_ws;
  float* wh1 = ws;                                            // 2097152 f
  unsigned short* bt1 = (unsigned short*)(wh1 + 2097152);     // 2097152 u16
  float* e1a = wh1 + 2097152 + 1048576;
  float* e2a = e1a + 8192;
  float* sinv1 = e2a + 8192;
  float* wh2 = sinv1 + 8192;                                  // 131072 f
  unsigned short* bt2 = (unsigned short*)(wh2 + 131072);      // 131072 u16
  float* e1b = wh2 + 131072 + 65536;
  float* e2b = e1b + 8192;
  float* sinv2 = e2b + 8192;
  unsigned* bits = (unsigned*)(sinv2 + 8192);                 // 2097152 u32

  pack_adj_k<<<8192, 256, 0, stream>>>(adj, bits);

  // ---- layer 1 ----
  gemm_f32_k<<<dim3(64, 4), 256, 0, stream>>>(x, W1, wh1, 8192, 512, 256);
  calc_e_k<<<2048, 256, 0, stream>>>(wh1, a1, e1a, e2a, 256);
  transpose_bf16_k<<<dim3(8, 256), dim3(32, 8), 0, stream>>>(wh1, bt1, 8192, 256);
  rowsum_k<<<2048, 256, 0, stream>>>(bits, e1a, e2a, sinv1);
  fused_att_agg1_k<<<256, 512, 0, stream>>>(bits, e1a, e2a, sinv1, bt1, att1, h1);

  // ---- layer 2 ----
  gemm_small_k<<<512, 256, 0, stream>>>(h1, W2, wh2, 256, 16);
  calc_e_k<<<2048, 256, 0, stream>>>(wh2, a2, e1b, e2b, 16);
  transpose_bf16_k<<<dim3(1, 256), dim3(32, 8), 0, stream>>>(wh2, bt2, 8192, 16);
  rowsum_k<<<2048, 256, 0, stream>>>(bits, e1b, e2b, sinv2);
  fused_att_agg2_k<<<256, 512, 0, stream>>>(bits, e1b, e2b, sinv2, bt2, att2, out);
}